// Round 6
// baseline (939.095 us; speedup 1.0000x reference)
//
#include <hip/hip_runtime.h>

#define NCLUST 256      // clusters 1..256 (cluster 0 = CLID_UNMATCHED, excluded)
#define NFEAT  64
#define NBLK_A 256      // 1 block/CU (129 KB LDS), 16 waves each
#define BIGF   1e30f

typedef __attribute__((ext_vector_type(8))) short  short8v;   // 8 x bf16
typedef __attribute__((ext_vector_type(4))) float  float4v;

// ---- static device scratch (rewritten fully every call) ----
__device__ __align__(16) float  g_partials [(size_t)NBLK_A * NCLUST * NFEAT]; // per-block sums
__device__ __align__(16) float  g_partials2[(size_t)NBLK_A * NCLUST * NFEAT]; // per-block sumsq
__device__ float  g_pcnt[NBLK_A * NCLUST];
__device__ float  g_cnt[NCLUST];
__device__ __align__(16) double g_means64[NCLUST * NFEAT];
__device__ __align__(16) float  g_means32[NCLUST * NFEAT];
__device__ __align__(16) unsigned short g_tmplbf[NCLUST * NFEAT]; // swizzled bf16 templates
__device__ double g_tn64[NCLUST];
__device__ double g_std64[NCLUST];
__device__ float  g_std32[NCLUST];
__device__ float2 g_ktab[NCLUST];         // (tn_f32, thr2_f32 or -1 if invalid)
__device__ int    g_valid[NCLUST];
__device__ int    g_list[1000000];
__device__ int    g_nlist;

static __device__ __forceinline__ unsigned short f2bf(float x) {
    union { float f; unsigned u; } v; v.f = x;
    unsigned r = v.u + 0x7fffu + ((v.u >> 16) & 1u);   // RNE
    return (unsigned short)(r >> 16);
}

// ---------------- Z ----------------
__global__ void kzero() { if (threadIdx.x == 0) g_nlist = 0; }

// ---------------- A: per-block segment sums. 16 waves/CU + software pipeline. ----------------
// Lane = feature. Per spike: 2 fire-and-forget ds_add (sum, sumsq) + lane0 count.
// R5 bug: 4 waves/CU (1/SIMD) + compiler fusing load/use per spike -> MLP=1,
// one full HBM latency per spike. Fix: 1024-thread block (16 waves/CU) +
// explicit A/B register double-buffer with sched_barrier(0) pinning the
// next-batch loads above the atomic phase.
__global__ __launch_bounds__(1024, 4) void kstats(const float* __restrict__ spikes,
                                                  const int* __restrict__ sidx, int n) {
    __shared__ float lsum[NCLUST * NFEAT]; // 64 KiB
    __shared__ float lsq [NCLUST * NFEAT]; // 64 KiB
    __shared__ float lcnt[NCLUST];
    for (int idx = threadIdx.x; idx < NCLUST * NFEAT; idx += 1024) { lsum[idx] = 0.f; lsq[idx] = 0.f; }
    if (threadIdx.x < NCLUST) lcnt[threadIdx.x] = 0.f;
    __syncthreads();

    const int lane = threadIdx.x & 63;
    const int wave = threadIdx.x >> 6;          // 0..15
    const int per  = (n + gridDim.x - 1) / gridDim.x;
    const int s0   = blockIdx.x * per;
    const int s1   = min(n, s0 + per);
    const int stride = 16 * 16;                 // 16 waves x 16 spikes

    float vA[16], vB[16]; int cA[16], cB[16];

    int ib = s0 + wave * 16;
    if (ib < s1) {
        #pragma unroll
        for (int j = 0; j < 16; ++j) {          // prologue: batch 0
            int i = ib + j;
            int rc = (i < s1) ? i : (s1 - 1);
            vA[j] = spikes[(size_t)rc * NFEAT + lane];
            cA[j] = (i < s1) ? sidx[i] : 0;
        }
    }

    for (; ib < s1; ib += stride) {
        const int ibn = ib + stride;
        if (ibn < s1) {                          // issue NEXT batch loads first
            #pragma unroll
            for (int j = 0; j < 16; ++j) {
                int i = ibn + j;
                int rc = (i < s1) ? i : (s1 - 1);
                vB[j] = spikes[(size_t)rc * NFEAT + lane];
                cB[j] = (i < s1) ? sidx[i] : 0;
            }
        }
        __builtin_amdgcn_sched_barrier(0);       // keep prefetch above the DS phase

        #pragma unroll
        for (int j = 0; j < 16; ++j) {           // process CURRENT batch (already landed)
            int c = cA[j];                       // wave-uniform
            if (c != 0) {
                float v = vA[j];
                int off = (c - 1) * NFEAT + lane;
                atomicAdd(&lsum[off], v);
                atomicAdd(&lsq[off],  v * v);
                if (lane == 0) atomicAdd(&lcnt[c - 1], 1.0f);
            }
        }
        #pragma unroll
        for (int j = 0; j < 16; ++j) { vA[j] = vB[j]; cA[j] = cB[j]; }
    }
    __syncthreads();

    size_t base = (size_t)blockIdx.x * (NCLUST * NFEAT);
    for (int idx = threadIdx.x; idx < NCLUST * NFEAT; idx += 1024) {
        g_partials [base + idx] = lsum[idx];
        g_partials2[base + idx] = lsq[idx];
    }
    if (threadIdx.x < NCLUST)
        g_pcnt[blockIdx.x * NCLUST + threadIdx.x] = lcnt[threadIdx.x];
}

// ---------------- A2: deterministic f64 reduce -> means / cnt / ssq / tn / std ----------------
__global__ __launch_bounds__(256) void kfinal() {
    const int c = blockIdx.x;                 // cluster c+1
    __shared__ double red [4][NFEAT];
    __shared__ double redq[4][NFEAT];
    __shared__ double smean[NFEAT];
    __shared__ double sh_cnt;
    const int f = threadIdx.x & 63, j = threadIdx.x >> 6;

    double acc = 0.0, accq = 0.0;
    for (int b = j; b < NBLK_A; b += 4) {
        acc  += (double)g_partials [(size_t)b * (NCLUST * NFEAT) + c * NFEAT + f];
        accq += (double)g_partials2[(size_t)b * (NCLUST * NFEAT) + c * NFEAT + f];
    }
    red[j][f] = acc; redq[j][f] = accq;

    if (threadIdx.x < 64) {
        double ca = 0.0;
        for (int b = threadIdx.x; b < NBLK_A; b += 64)
            ca += (double)g_pcnt[b * NCLUST + c];
        #pragma unroll
        for (int o = 32; o; o >>= 1) ca += __shfl_xor(ca, o);
        if (threadIdx.x == 0) sh_cnt = ca;
    }
    __syncthreads();

    if (threadIdx.x < NFEAT) {
        double s = ((red[0][f] + red[1][f]) + red[2][f]) + red[3][f];
        double cnt = sh_cnt;
        double mean = (cnt > 0.0) ? s / cnt : 0.0;
        g_means64[c * NFEAT + f] = mean;
        g_means32[c * NFEAT + f] = (float)mean;
        smean[f] = mean;
        redq[0][f] = ((redq[0][f] + redq[1][f]) + redq[2][f]) + redq[3][f];
    }
    __syncthreads();
    if (threadIdx.x == 0) {
        double tn = 0.0, ssq = 0.0;
        for (int q = 0; q < NFEAT; ++q) { tn += smean[q] * smean[q]; ssq += redq[0][q]; }
        double cnt = sh_cnt;
        double var = (cnt > 0.0) ? ssq / cnt - tn : 0.0;
        if (var < 0.0) var = 0.0;
        double sd = sqrt(var);
        g_tn64[c] = tn; g_std64[c] = sd; g_std32[c] = (float)sd;
        g_cnt[c] = (float)cnt;
    }
}

// ---------------- A3: median, validity, thresholds, + bf16 template pre-convert ----------------
__global__ __launch_bounds__(256) void kmedian() {
    __shared__ float svals[NCLUST];
    __shared__ int   svalid[NCLUST];
    __shared__ float mred[2];
    int t = threadIdx.x;
    if (t == 0) { mred[0] = 0.f; mred[1] = 0.f; }
    float cnt = g_cnt[t];
    int v0 = (cnt > 0.f) ? 1 : 0;
    float sd = g_std32[t];
    svals[t] = sd; svalid[t] = v0;
    __syncthreads();

    int m = 0, rank = 0;
    for (int jj = 0; jj < NCLUST; ++jj) {
        if (svalid[jj]) {
            ++m;
            float sj = svals[jj];
            if (sj < sd || (sj == sd && jj < t)) ++rank;
        }
    }
    if (v0) {
        if (rank == (m - 1) / 2) mred[0] = sd;
        if (rank == m / 2)       mred[1] = sd;
    }
    __syncthreads();
    float med = 0.5f * (mred[0] + mred[1]);

    int valid = v0 && (sd <= 3.0f * med);
    double sd64 = g_std64[t];
    float thr2 = valid ? (float)((1.5 * sd64) * (1.5 * sd64)) : -1.0f;
    g_valid[t] = valid;
    g_ktab[t]  = make_float2((float)g_tn64[t], thr2);

    // pre-convert templates to bf16 in the SWIZZLED layout (once, not per kmatch block)
    for (int q = threadIdx.x; q < NCLUST * 8; q += 256) {
        int c = q >> 3, g = q & 7;
        float4 u0 = *(const float4*)&g_means32[c * NFEAT + g * 8];
        float4 u1 = *(const float4*)&g_means32[c * NFEAT + g * 8 + 4];
        short8v h;
        h[0] = (short)f2bf(u0.x); h[1] = (short)f2bf(u0.y);
        h[2] = (short)f2bf(u0.z); h[3] = (short)f2bf(u0.w);
        h[4] = (short)f2bf(u1.x); h[5] = (short)f2bf(u1.y);
        h[6] = (short)f2bf(u1.z); h[7] = (short)f2bf(u1.w);
        unsigned byteoff = (unsigned)c * 128u + (((unsigned)g * 16u) ^ (((unsigned)c & 7u) << 4));
        *(short8v*)((char*)g_tmplbf + byteoff) = h;
    }
}

// ---------------- C: MFMA bulk min pass, 256 spikes per block ----------------
// mfma_f32_16x16x32_bf16: A lane l -> row=l&15, k=(l>>4)*8+j ; B lane l -> col=l&15, same k map.
// D lane l, reg r -> row=(l>>4)*4+r, col=l&15  [verified layout, m89]
__global__ __launch_bounds__(256) void kmatch(const float* __restrict__ spikes,
                                              const int* __restrict__ sidx,
                                              const unsigned char* __restrict__ midx,
                                              float* __restrict__ out, int n) {
    __shared__ __align__(16) unsigned short tml[NCLUST * NFEAT]; // 32 KiB swizzled bf16
    __shared__ float2 ktab_sh[NCLUST];

    // stage pre-swizzled templates: linear 16B copies
    for (int idx = threadIdx.x * 8; idx < NCLUST * NFEAT; idx += 256 * 8)
        *(short8v*)&tml[idx] = *(const short8v*)&g_tmplbf[idx];
    if (threadIdx.x < NCLUST) ktab_sh[threadIdx.x] = g_ktab[threadIdx.x];
    __syncthreads();

    const int lane = threadIdx.x & 63, wave = threadIdx.x >> 6;
    const int row  = lane & 15, grp = lane >> 4;
    const int i0w  = blockIdx.x * 256 + wave * 64;   // this wave's 64 spikes

    #pragma unroll 1
    for (int sb = 0; sb < 4; ++sb) {
        const int i0 = i0w + sb * 16;

        // ---- A fragments (spikes straight from global, f32 -> bf16) ----
        int ri = i0 + row;
        int rc = (ri < n) ? ri : (n - 1);
        const float* sp = spikes + (size_t)rc * NFEAT + grp * 8;
        float4 a0 = *(const float4*)(sp);
        float4 a1 = *(const float4*)(sp + 4);
        float4 a2 = *(const float4*)(sp + 32);
        float4 a3 = *(const float4*)(sp + 36);
        short8v af0, af1;
        af0[0] = (short)f2bf(a0.x); af0[1] = (short)f2bf(a0.y);
        af0[2] = (short)f2bf(a0.z); af0[3] = (short)f2bf(a0.w);
        af0[4] = (short)f2bf(a1.x); af0[5] = (short)f2bf(a1.y);
        af0[6] = (short)f2bf(a1.z); af0[7] = (short)f2bf(a1.w);
        af1[0] = (short)f2bf(a2.x); af1[1] = (short)f2bf(a2.y);
        af1[2] = (short)f2bf(a2.z); af1[3] = (short)f2bf(a2.w);
        af1[4] = (short)f2bf(a3.x); af1[5] = (short)f2bf(a3.y);
        af1[6] = (short)f2bf(a3.z); af1[7] = (short)f2bf(a3.w);

        // sn (|s|^2) in f32 from ORIGINAL f32 values; reduce across the 4 k-groups
        float pss = a0.x*a0.x + a0.y*a0.y + a0.z*a0.z + a0.w*a0.w
                  + a1.x*a1.x + a1.y*a1.y + a1.z*a1.z + a1.w*a1.w
                  + a2.x*a2.x + a2.y*a2.y + a2.z*a2.z + a2.w*a2.w
                  + a3.x*a3.x + a3.y*a3.y + a3.z*a3.z + a3.w*a3.w;
        pss += __shfl_xor(pss, 16);
        pss += __shfl_xor(pss, 32);          // now sn of row `row` on every lane

        float snr[4];
        #pragma unroll
        for (int r = 0; r < 4; ++r) snr[r] = __shfl(pss, grp * 4 + r);

        float d2min[4] = {3.4e38f, 3.4e38f, 3.4e38f, 3.4e38f};

        #pragma unroll 2
        for (int nt = 0; nt < 16; ++nt) {
            int c = nt * 16 + row;
            unsigned co = (unsigned)c * 128u;
            unsigned sw = (((unsigned)c & 7u) << 4);
            short8v b0 = *(short8v*)((char*)tml + (co + (((unsigned)grp * 16u) ^ sw)));
            short8v b1 = *(short8v*)((char*)tml + (co + ((((unsigned)grp + 4u) * 16u) ^ sw)));
            float4v acc = {0.f, 0.f, 0.f, 0.f};
            acc = __builtin_amdgcn_mfma_f32_16x16x32_bf16(af0, b0, acc, 0, 0, 0);
            acc = __builtin_amdgcn_mfma_f32_16x16x32_bf16(af1, b1, acc, 0, 0, 0);
            float2 kt = ktab_sh[c];
            #pragma unroll
            for (int r = 0; r < 4; ++r) {
                float d2 = (snr[r] - 2.0f * acc[r]) + kt.x;
                if (!(d2 > kt.y)) d2min[r] = fminf(d2min[r], d2);  // thr2=-1 => masked
            }
        }

        // min over the 16 cluster-lanes (xor 1,2,4,8)
        #pragma unroll
        for (int o = 1; o < 16; o <<= 1) {
            #pragma unroll
            for (int r = 0; r < 4; ++r) d2min[r] = fminf(d2min[r], __shfl_xor(d2min[r], o));
        }
        if (row == 0) {
            #pragma unroll
            for (int r = 0; r < 4; ++r) {
                int i = i0 + grp * 4 + r;
                if (i < n) {
                    float dm = d2min[r];
                    out[2 * (size_t)n + i] = (dm > 1e37f) ? BIGF : sqrtf(fmaxf(dm, 0.f));
                }
            }
        }
    }

    // pass-through outputs + unmatched list (256 threads cover this block's 256 spikes)
    int i = blockIdx.x * 256 + threadIdx.x;
    if (i < n) {
        int si = sidx[i];
        out[i]             = (float)si;
        out[(size_t)n + i] = midx[i] ? 1.0f : 0.0f;
        if (si == 0) {
            int p = atomicAdd(&g_nlist, 1);
            if (p < 1000000) g_list[p] = i;
        }
    }
}

// ---------------- D: precise f64 argmin, WAVE-PER-SPIKE (lane = feature) ----------------
__global__ __launch_bounds__(256) void kprecise(const float* __restrict__ spikes,
                                                float* __restrict__ out, int n) {
    const int lane  = threadIdx.x & 63;
    const int gwave = (blockIdx.x * 256 + threadIdx.x) >> 6;
    const int nwave = (gridDim.x * 256) >> 6;
    const int nt    = g_nlist;

    for (int t = gwave; t < nt; t += nwave) {
        const int i = g_list[t];
        const double sf = (double)spikes[(size_t)i * NFEAT + lane];

        double sn = sf * sf;
        #pragma unroll
        for (int o = 32; o; o >>= 1) sn += __shfl_xor(sn, o);

        double dmin = 1e30; int best = 0;
        #pragma unroll 1
        for (int k = 0; k < NCLUST; k += 2) {
            double p0 = sf * g_means64[(size_t)(k + 0) * NFEAT + lane];
            double p1 = sf * g_means64[(size_t)(k + 1) * NFEAT + lane];
            #pragma unroll
            for (int o = 32; o; o >>= 1) {
                p0 += __shfl_xor(p0, o);
                p1 += __shfl_xor(p1, o);
            }
            #pragma unroll
            for (int j = 0; j < 2; ++j) {
                const int kk = k + j;
                const double dot = j ? p1 : p0;
                if (!g_valid[kk]) continue;
                double d2 = (sn - 2.0 * dot) + g_tn64[kk];
                double dist = sqrt(fmax(d2, 0.0));
                if (dist > 1.5 * g_std64[kk]) continue;
                if (dist < dmin) { dmin = dist; best = kk + 1; }  // ascending k => first-index ties
            }
        }
        if (dmin >= 256.0) best = 0;   // FIRST_MATCH_MAX_DIST * N_SAMPLES

        if (lane == 0) {
            out[i]                 = (float)best;
            out[(size_t)n + i]     = (best != 0) ? 1.0f : 0.0f;
            out[2 * (size_t)n + i] = (float)dmin;
        }
    }
}

extern "C" void kernel_launch(void* const* d_in, const int* in_sizes, int n_in,
                              void* d_out, int out_size, void* d_ws, size_t ws_size,
                              hipStream_t stream) {
    const float*         spikes = (const float*)d_in[0];
    const int*           sidx   = (const int*)d_in[1];
    const unsigned char* midx   = (const unsigned char*)d_in[2];
    float*               out    = (float*)d_out;
    const int n = in_sizes[1];

    kzero<<<1, 64, 0, stream>>>();
    kstats<<<NBLK_A, 1024, 0, stream>>>(spikes, sidx, n);
    kfinal<<<NCLUST, 256, 0, stream>>>();
    kmedian<<<1, 256, 0, stream>>>();
    int nblk = (n + 255) / 256;
    kmatch<<<nblk, 256, 0, stream>>>(spikes, sidx, midx, out, n);
    kprecise<<<1024, 256, 0, stream>>>(spikes, out, n);
}

// Round 7
// 382.568 us; speedup vs baseline: 2.4547x; 2.4547x over previous
//
#include <hip/hip_runtime.h>

#define NCLUST 256      // clusters 1..256 (cluster 0 = CLID_UNMATCHED, excluded)
#define NFEAT  64
#define NBLK_A 256      // 1 block/CU
#define BIGF   1e30f

#define SUM_SCALE  1073741824.0      // 2^30
#define SSQ_SCALE  16777216.0        // 2^24
#define INV_SUM_SCALE (1.0 / 1073741824.0)
#define INV_SSQ_SCALE (1.0 / 16777216.0)

typedef __attribute__((ext_vector_type(8))) short  short8v;   // 8 x bf16
typedef __attribute__((ext_vector_type(4))) float  float4v;
typedef unsigned long long u64;

// ---- static device scratch (rewritten fully every call) ----
// fixed-point integer partials: order-free exact sums
__device__ __align__(16) u64      g_psum[(size_t)NCLUST * NBLK_A * NFEAT]; // [c][b][f] 33.5MB
__device__ __align__(16) u64      g_pssq[(size_t)NCLUST * NBLK_A * 8];     // [c][b][8]
__device__ unsigned g_pcnt[NCLUST * NBLK_A * 8];                           // [c][b][8]
__device__ float  g_cnt[NCLUST];
__device__ __align__(16) double g_means64[NCLUST * NFEAT];
__device__ __align__(16) float  g_means32[NCLUST * NFEAT];
__device__ __align__(16) unsigned short g_tmplbf[NCLUST * NFEAT]; // swizzled bf16 templates
__device__ double g_tn64[NCLUST];
__device__ double g_std64[NCLUST];
__device__ float  g_std32[NCLUST];
__device__ float2 g_ktab[NCLUST];         // (tn_f32, thr2_f32 or -1 if invalid)
__device__ int    g_valid[NCLUST];
__device__ int    g_list[1000000];
__device__ int    g_nlist;

static __device__ __forceinline__ unsigned short f2bf(float x) {
    union { float f; unsigned u; } v; v.f = x;
    unsigned r = v.u + 0x7fffu + ((v.u >> 16) & 1u);   // RNE
    return (unsigned short)(r >> 16);
}

// ---------------- Z ----------------
__global__ void kzero() { if (threadIdx.x == 0) g_nlist = 0; }

// ---------------- A: segment sums via NATIVE u64 LDS atomics (fixed-point) ----------------
// R4-R6 post-mortem: time tracked the count of float LDS atomicAdds (~not BW,
// not occupancy, not conflicts) -> fp atomics likely compile to returning CAS
// loops (2x ~120cy dependent LDS round-trips each). Fix: integer ds_add_u64,
// fire-and-forget, and exactly deterministic (integer adds commute).
__global__ __launch_bounds__(1024, 4) void kstats(const float* __restrict__ spikes,
                                                  const int* __restrict__ sidx, int n) {
    __shared__ u64      lsum[NCLUST * NFEAT]; // 128 KiB  (c,f) fixed-point 2^30
    __shared__ u64      lssq[NCLUST * 8];     // 16 KiB   (c, lane&7) fixed-point 2^24
    __shared__ unsigned lcnt[NCLUST * 8];     // 8 KiB    (c, wave&7)
    for (int idx = threadIdx.x; idx < NCLUST * NFEAT; idx += 1024) lsum[idx] = 0ull;
    for (int idx = threadIdx.x; idx < NCLUST * 8; idx += 1024) { lssq[idx] = 0ull; lcnt[idx] = 0u; }
    __syncthreads();

    const int lane = threadIdx.x & 63;
    const int wave = threadIdx.x >> 6;          // 0..15
    const int per  = (n + gridDim.x - 1) / gridDim.x;
    const int s0   = blockIdx.x * per;
    const int s1   = min(n, s0 + per);

    for (int ib = s0 + wave * 8; ib < s1; ib += 16 * 8) {
        float v[8]; int c[8];
        #pragma unroll
        for (int j = 0; j < 8; ++j) {
            int i  = ib + j;
            int rc = (i < s1) ? i : (s1 - 1);
            v[j] = spikes[(size_t)rc * NFEAT + lane];
            c[j] = (i < s1) ? sidx[i] : 0;
        }
        #pragma unroll
        for (int j = 0; j < 8; ++j) {
            int cj = c[j];
            if (cj != 0) {
                double vd = (double)v[j];
                long long sv = llrint(vd * SUM_SCALE);
                long long qv = llrint(vd * vd * SSQ_SCALE);
                atomicAdd(&lsum[(cj - 1) * NFEAT + lane], (u64)sv);
                atomicAdd(&lssq[(cj - 1) * 8 + (lane & 7)], (u64)qv);
                if (lane == 0) atomicAdd(&lcnt[(cj - 1) * 8 + (wave & 7)], 1u);
            }
        }
    }
    __syncthreads();

    const int b = blockIdx.x;
    for (int idx = threadIdx.x; idx < NCLUST * NFEAT; idx += 1024) {
        int c = idx >> 6, f = idx & 63;
        g_psum[((size_t)c * NBLK_A + b) * NFEAT + f] = lsum[idx];
    }
    for (int idx = threadIdx.x; idx < NCLUST * 8; idx += 1024) {
        int c = idx >> 3, k = idx & 7;
        g_pssq[((size_t)c * NBLK_A + b) * 8 + k] = lssq[idx];
        g_pcnt[(c * NBLK_A + b) * 8 + k]         = lcnt[idx];
    }
}

// ---------------- A2: exact integer reduce -> f64 means / cnt / ssq / tn / std ----------------
__global__ __launch_bounds__(256) void kfinal() {
    const int c = blockIdx.x;                 // cluster c+1
    __shared__ u64 redS[4][NFEAT];
    __shared__ double smean[NFEAT];
    __shared__ double sh_cnt, sh_ssq;
    const int f = threadIdx.x & 63, j = threadIdx.x >> 6;

    u64 acc = 0ull;
    for (int b = j; b < NBLK_A; b += 4)
        acc += g_psum[((size_t)c * NBLK_A + b) * NFEAT + f];   // coalesced: [c][b][f]
    redS[j][f] = acc;

    if (threadIdx.x < 64) {
        u64 sq = 0ull; unsigned cn = 0u;
        for (int e = threadIdx.x; e < NBLK_A * 8; e += 64) {
            sq += g_pssq[(size_t)c * NBLK_A * 8 + e];
            cn += g_pcnt[c * NBLK_A * 8 + e];
        }
        #pragma unroll
        for (int o = 32; o; o >>= 1) {
            sq += __shfl_xor(sq, o);
            cn += __shfl_xor(cn, o);
        }
        if (threadIdx.x == 0) {
            sh_cnt = (double)cn;
            sh_ssq = (double)(long long)sq * INV_SSQ_SCALE;
        }
    }
    __syncthreads();

    if (threadIdx.x < NFEAT) {
        long long tot = (long long)(redS[0][f] + redS[1][f] + redS[2][f] + redS[3][f]);
        double cnt = sh_cnt;
        double mean = (cnt > 0.0) ? ((double)tot * INV_SUM_SCALE) / cnt : 0.0;
        g_means64[c * NFEAT + f] = mean;
        g_means32[c * NFEAT + f] = (float)mean;
        smean[f] = mean;
    }
    __syncthreads();
    if (threadIdx.x == 0) {
        double tn = 0.0;
        for (int q = 0; q < NFEAT; ++q) tn += smean[q] * smean[q];
        double cnt = sh_cnt;
        double var = (cnt > 0.0) ? sh_ssq / cnt - tn : 0.0;
        if (var < 0.0) var = 0.0;
        double sd = sqrt(var);
        g_tn64[c] = tn; g_std64[c] = sd; g_std32[c] = (float)sd;
        g_cnt[c] = (float)cnt;
    }
}

// ---------------- A3: median, validity, thresholds, + bf16 template pre-convert ----------------
__global__ __launch_bounds__(256) void kmedian() {
    __shared__ float svals[NCLUST];
    __shared__ int   svalid[NCLUST];
    __shared__ float mred[2];
    int t = threadIdx.x;
    if (t == 0) { mred[0] = 0.f; mred[1] = 0.f; }
    float cnt = g_cnt[t];
    int v0 = (cnt > 0.f) ? 1 : 0;
    float sd = g_std32[t];
    svals[t] = sd; svalid[t] = v0;
    __syncthreads();

    int m = 0, rank = 0;
    for (int jj = 0; jj < NCLUST; ++jj) {
        if (svalid[jj]) {
            ++m;
            float sj = svals[jj];
            if (sj < sd || (sj == sd && jj < t)) ++rank;
        }
    }
    if (v0) {
        if (rank == (m - 1) / 2) mred[0] = sd;
        if (rank == m / 2)       mred[1] = sd;
    }
    __syncthreads();
    float med = 0.5f * (mred[0] + mred[1]);

    int valid = v0 && (sd <= 3.0f * med);
    double sd64 = g_std64[t];
    float thr2 = valid ? (float)((1.5 * sd64) * (1.5 * sd64)) : -1.0f;
    g_valid[t] = valid;
    g_ktab[t]  = make_float2((float)g_tn64[t], thr2);

    // pre-convert templates to bf16 in the SWIZZLED layout (once, not per kmatch block)
    for (int q = threadIdx.x; q < NCLUST * 8; q += 256) {
        int c = q >> 3, g = q & 7;
        float4 u0 = *(const float4*)&g_means32[c * NFEAT + g * 8];
        float4 u1 = *(const float4*)&g_means32[c * NFEAT + g * 8 + 4];
        short8v h;
        h[0] = (short)f2bf(u0.x); h[1] = (short)f2bf(u0.y);
        h[2] = (short)f2bf(u0.z); h[3] = (short)f2bf(u0.w);
        h[4] = (short)f2bf(u1.x); h[5] = (short)f2bf(u1.y);
        h[6] = (short)f2bf(u1.z); h[7] = (short)f2bf(u1.w);
        unsigned byteoff = (unsigned)c * 128u + (((unsigned)g * 16u) ^ (((unsigned)c & 7u) << 4));
        *(short8v*)((char*)g_tmplbf + byteoff) = h;
    }
}

// ---------------- C: MFMA bulk min pass, 256 spikes per block ----------------
// mfma_f32_16x16x32_bf16: A lane l -> row=l&15, k=(l>>4)*8+j ; B lane l -> col=l&15, same k map.
// D lane l, reg r -> row=(l>>4)*4+r, col=l&15  [verified layout, m89]
__global__ __launch_bounds__(256) void kmatch(const float* __restrict__ spikes,
                                              const int* __restrict__ sidx,
                                              const unsigned char* __restrict__ midx,
                                              float* __restrict__ out, int n) {
    __shared__ __align__(16) unsigned short tml[NCLUST * NFEAT]; // 32 KiB swizzled bf16
    __shared__ float2 ktab_sh[NCLUST];

    // stage pre-swizzled templates: linear 16B copies
    for (int idx = threadIdx.x * 8; idx < NCLUST * NFEAT; idx += 256 * 8)
        *(short8v*)&tml[idx] = *(const short8v*)&g_tmplbf[idx];
    if (threadIdx.x < NCLUST) ktab_sh[threadIdx.x] = g_ktab[threadIdx.x];
    __syncthreads();

    const int lane = threadIdx.x & 63, wave = threadIdx.x >> 6;
    const int row  = lane & 15, grp = lane >> 4;
    const int i0w  = blockIdx.x * 256 + wave * 64;   // this wave's 64 spikes

    #pragma unroll 1
    for (int sb = 0; sb < 4; ++sb) {
        const int i0 = i0w + sb * 16;

        // ---- A fragments (spikes straight from global, f32 -> bf16) ----
        int ri = i0 + row;
        int rc = (ri < n) ? ri : (n - 1);
        const float* sp = spikes + (size_t)rc * NFEAT + grp * 8;
        float4 a0 = *(const float4*)(sp);
        float4 a1 = *(const float4*)(sp + 4);
        float4 a2 = *(const float4*)(sp + 32);
        float4 a3 = *(const float4*)(sp + 36);
        short8v af0, af1;
        af0[0] = (short)f2bf(a0.x); af0[1] = (short)f2bf(a0.y);
        af0[2] = (short)f2bf(a0.z); af0[3] = (short)f2bf(a0.w);
        af0[4] = (short)f2bf(a1.x); af0[5] = (short)f2bf(a1.y);
        af0[6] = (short)f2bf(a1.z); af0[7] = (short)f2bf(a1.w);
        af1[0] = (short)f2bf(a2.x); af1[1] = (short)f2bf(a2.y);
        af1[2] = (short)f2bf(a2.z); af1[3] = (short)f2bf(a2.w);
        af1[4] = (short)f2bf(a3.x); af1[5] = (short)f2bf(a3.y);
        af1[6] = (short)f2bf(a3.z); af1[7] = (short)f2bf(a3.w);

        // sn (|s|^2) in f32 from ORIGINAL f32 values; reduce across the 4 k-groups
        float pss = a0.x*a0.x + a0.y*a0.y + a0.z*a0.z + a0.w*a0.w
                  + a1.x*a1.x + a1.y*a1.y + a1.z*a1.z + a1.w*a1.w
                  + a2.x*a2.x + a2.y*a2.y + a2.z*a2.z + a2.w*a2.w
                  + a3.x*a3.x + a3.y*a3.y + a3.z*a3.z + a3.w*a3.w;
        pss += __shfl_xor(pss, 16);
        pss += __shfl_xor(pss, 32);          // now sn of row `row` on every lane

        float snr[4];
        #pragma unroll
        for (int r = 0; r < 4; ++r) snr[r] = __shfl(pss, grp * 4 + r);

        float d2min[4] = {3.4e38f, 3.4e38f, 3.4e38f, 3.4e38f};

        #pragma unroll 2
        for (int nt = 0; nt < 16; ++nt) {
            int c = nt * 16 + row;
            unsigned co = (unsigned)c * 128u;
            unsigned sw = (((unsigned)c & 7u) << 4);
            short8v b0 = *(short8v*)((char*)tml + (co + (((unsigned)grp * 16u) ^ sw)));
            short8v b1 = *(short8v*)((char*)tml + (co + ((((unsigned)grp + 4u) * 16u) ^ sw)));
            float4v acc = {0.f, 0.f, 0.f, 0.f};
            acc = __builtin_amdgcn_mfma_f32_16x16x32_bf16(af0, b0, acc, 0, 0, 0);
            acc = __builtin_amdgcn_mfma_f32_16x16x32_bf16(af1, b1, acc, 0, 0, 0);
            float2 kt = ktab_sh[c];
            #pragma unroll
            for (int r = 0; r < 4; ++r) {
                float d2 = (snr[r] - 2.0f * acc[r]) + kt.x;
                if (!(d2 > kt.y)) d2min[r] = fminf(d2min[r], d2);  // thr2=-1 => masked
            }
        }

        // min over the 16 cluster-lanes (xor 1,2,4,8)
        #pragma unroll
        for (int o = 1; o < 16; o <<= 1) {
            #pragma unroll
            for (int r = 0; r < 4; ++r) d2min[r] = fminf(d2min[r], __shfl_xor(d2min[r], o));
        }
        if (row == 0) {
            #pragma unroll
            for (int r = 0; r < 4; ++r) {
                int i = i0 + grp * 4 + r;
                if (i < n) {
                    float dm = d2min[r];
                    out[2 * (size_t)n + i] = (dm > 1e37f) ? BIGF : sqrtf(fmaxf(dm, 0.f));
                }
            }
        }
    }

    // pass-through outputs + unmatched list (256 threads cover this block's 256 spikes)
    int i = blockIdx.x * 256 + threadIdx.x;
    if (i < n) {
        int si = sidx[i];
        out[i]             = (float)si;
        out[(size_t)n + i] = midx[i] ? 1.0f : 0.0f;
        if (si == 0) {
            int p = atomicAdd(&g_nlist, 1);
            if (p < 1000000) g_list[p] = i;
        }
    }
}

// ---------------- D: precise f64 argmin, WAVE-PER-SPIKE (lane = feature) ----------------
__global__ __launch_bounds__(256) void kprecise(const float* __restrict__ spikes,
                                                float* __restrict__ out, int n) {
    const int lane  = threadIdx.x & 63;
    const int gwave = (blockIdx.x * 256 + threadIdx.x) >> 6;
    const int nwave = (gridDim.x * 256) >> 6;
    const int nt    = g_nlist;

    for (int t = gwave; t < nt; t += nwave) {
        const int i = g_list[t];
        const double sf = (double)spikes[(size_t)i * NFEAT + lane];

        double sn = sf * sf;
        #pragma unroll
        for (int o = 32; o; o >>= 1) sn += __shfl_xor(sn, o);

        double dmin = 1e30; int best = 0;
        #pragma unroll 1
        for (int k = 0; k < NCLUST; k += 2) {
            double p0 = sf * g_means64[(size_t)(k + 0) * NFEAT + lane];
            double p1 = sf * g_means64[(size_t)(k + 1) * NFEAT + lane];
            #pragma unroll
            for (int o = 32; o; o >>= 1) {
                p0 += __shfl_xor(p0, o);
                p1 += __shfl_xor(p1, o);
            }
            #pragma unroll
            for (int j = 0; j < 2; ++j) {
                const int kk = k + j;
                const double dot = j ? p1 : p0;
                if (!g_valid[kk]) continue;
                double d2 = (sn - 2.0 * dot) + g_tn64[kk];
                double dist = sqrt(fmax(d2, 0.0));
                if (dist > 1.5 * g_std64[kk]) continue;
                if (dist < dmin) { dmin = dist; best = kk + 1; }  // ascending k => first-index ties
            }
        }
        if (dmin >= 256.0) best = 0;   // FIRST_MATCH_MAX_DIST * N_SAMPLES

        if (lane == 0) {
            out[i]                 = (float)best;
            out[(size_t)n + i]     = (best != 0) ? 1.0f : 0.0f;
            out[2 * (size_t)n + i] = (float)dmin;
        }
    }
}

extern "C" void kernel_launch(void* const* d_in, const int* in_sizes, int n_in,
                              void* d_out, int out_size, void* d_ws, size_t ws_size,
                              hipStream_t stream) {
    const float*         spikes = (const float*)d_in[0];
    const int*           sidx   = (const int*)d_in[1];
    const unsigned char* midx   = (const unsigned char*)d_in[2];
    float*               out    = (float*)d_out;
    const int n = in_sizes[1];

    kzero<<<1, 64, 0, stream>>>();
    kstats<<<NBLK_A, 1024, 0, stream>>>(spikes, sidx, n);
    kfinal<<<NCLUST, 256, 0, stream>>>();
    kmedian<<<1, 256, 0, stream>>>();
    int nblk = (n + 255) / 256;
    kmatch<<<nblk, 256, 0, stream>>>(spikes, sidx, midx, out, n);
    kprecise<<<1024, 256, 0, stream>>>(spikes, out, n);
}

// Round 8
// 250.359 us; speedup vs baseline: 3.7510x; 1.5281x over previous
//
#include <hip/hip_runtime.h>

#define NCLUST 256      // clusters 1..256 (cluster 0 = CLID_UNMATCHED, excluded)
#define NFEAT  64
#define NBLK_A 256      // 1 block/CU
#define BIGF   1e30f

#define SUM_SCALE  1073741824.0      // 2^30
#define SSQ_SCALE  16777216.0        // 2^24
#define INV_SUM_SCALE (1.0 / 1073741824.0)
#define INV_SSQ_SCALE (1.0 / 16777216.0)

typedef __attribute__((ext_vector_type(8))) short  short8v;   // 8 x bf16
typedef __attribute__((ext_vector_type(4))) float  float4v;
typedef unsigned long long u64;

// ---- static device scratch (rewritten fully every call) ----
// fixed-point integer partials: order-free exact sums
__device__ __align__(16) u64      g_psum[(size_t)NCLUST * NBLK_A * NFEAT]; // [c][b][f] 33.5MB
__device__ __align__(16) u64      g_pssq[(size_t)NCLUST * NBLK_A * 8];     // [c][b][8]
__device__ unsigned g_pcnt[NCLUST * NBLK_A * 8];                           // [c][b][8]
__device__ float  g_cnt[NCLUST];
__device__ __align__(16) double g_means64[NCLUST * NFEAT];
__device__ __align__(16) double g_means64T[NFEAT * NCLUST];   // transposed [f][c]
__device__ __align__(16) float  g_means32[NCLUST * NFEAT];
__device__ __align__(16) unsigned short g_tmplbf[NCLUST * NFEAT]; // swizzled bf16 templates
__device__ double g_tn64[NCLUST];
__device__ double g_std64[NCLUST];
__device__ float  g_std32[NCLUST];
__device__ float2 g_ktab[NCLUST];         // (tn_f32, thr2_f32 or -1 if invalid)
__device__ int    g_valid[NCLUST];
__device__ int    g_list[1000000];
__device__ int    g_nlist;

static __device__ __forceinline__ unsigned short f2bf(float x) {
    union { float f; unsigned u; } v; v.f = x;
    unsigned r = v.u + 0x7fffu + ((v.u >> 16) & 1u);   // RNE
    return (unsigned short)(r >> 16);
}

// ---------------- Z ----------------
__global__ void kzero() { if (threadIdx.x == 0) g_nlist = 0; }

// ---------------- A: segment sums via NATIVE u64 LDS atomics (fixed-point) ----------------
__global__ __launch_bounds__(1024, 4) void kstats(const float* __restrict__ spikes,
                                                  const int* __restrict__ sidx, int n) {
    __shared__ u64      lsum[NCLUST * NFEAT]; // 128 KiB  (c,f) fixed-point 2^30
    __shared__ u64      lssq[NCLUST * 8];     // 16 KiB   (c, lane&7) fixed-point 2^24
    __shared__ unsigned lcnt[NCLUST * 8];     // 8 KiB    (c, wave&7)
    for (int idx = threadIdx.x; idx < NCLUST * NFEAT; idx += 1024) lsum[idx] = 0ull;
    for (int idx = threadIdx.x; idx < NCLUST * 8; idx += 1024) { lssq[idx] = 0ull; lcnt[idx] = 0u; }
    __syncthreads();

    const int lane = threadIdx.x & 63;
    const int wave = threadIdx.x >> 6;          // 0..15
    const int per  = (n + gridDim.x - 1) / gridDim.x;
    const int s0   = blockIdx.x * per;
    const int s1   = min(n, s0 + per);

    for (int ib = s0 + wave * 8; ib < s1; ib += 16 * 8) {
        float v[8]; int c[8];
        #pragma unroll
        for (int j = 0; j < 8; ++j) {
            int i  = ib + j;
            int rc = (i < s1) ? i : (s1 - 1);
            v[j] = spikes[(size_t)rc * NFEAT + lane];
            c[j] = (i < s1) ? sidx[i] : 0;
        }
        #pragma unroll
        for (int j = 0; j < 8; ++j) {
            int cj = c[j];
            if (cj != 0) {
                double vd = (double)v[j];
                long long sv = llrint(vd * SUM_SCALE);
                long long qv = llrint(vd * vd * SSQ_SCALE);
                atomicAdd(&lsum[(cj - 1) * NFEAT + lane], (u64)sv);
                atomicAdd(&lssq[(cj - 1) * 8 + (lane & 7)], (u64)qv);
                if (lane == 0) atomicAdd(&lcnt[(cj - 1) * 8 + (wave & 7)], 1u);
            }
        }
    }
    __syncthreads();

    const int b = blockIdx.x;
    for (int idx = threadIdx.x; idx < NCLUST * NFEAT; idx += 1024) {
        int c = idx >> 6, f = idx & 63;
        g_psum[((size_t)c * NBLK_A + b) * NFEAT + f] = lsum[idx];
    }
    for (int idx = threadIdx.x; idx < NCLUST * 8; idx += 1024) {
        int c = idx >> 3, k = idx & 7;
        g_pssq[((size_t)c * NBLK_A + b) * 8 + k] = lssq[idx];
        g_pcnt[(c * NBLK_A + b) * 8 + k]         = lcnt[idx];
    }
}

// ---------------- A2: exact integer reduce -> f64 means / cnt / ssq / tn / std ----------------
__global__ __launch_bounds__(256) void kfinal() {
    const int c = blockIdx.x;                 // cluster c+1
    __shared__ u64 redS[4][NFEAT];
    __shared__ double smean[NFEAT];
    __shared__ double sh_cnt, sh_ssq;
    const int f = threadIdx.x & 63, j = threadIdx.x >> 6;

    u64 acc = 0ull;
    for (int b = j; b < NBLK_A; b += 4)
        acc += g_psum[((size_t)c * NBLK_A + b) * NFEAT + f];   // coalesced: [c][b][f]
    redS[j][f] = acc;

    if (threadIdx.x < 64) {
        u64 sq = 0ull; unsigned cn = 0u;
        for (int e = threadIdx.x; e < NBLK_A * 8; e += 64) {
            sq += g_pssq[(size_t)c * NBLK_A * 8 + e];
            cn += g_pcnt[c * NBLK_A * 8 + e];
        }
        #pragma unroll
        for (int o = 32; o; o >>= 1) {
            sq += __shfl_xor(sq, o);
            cn += __shfl_xor(cn, o);
        }
        if (threadIdx.x == 0) {
            sh_cnt = (double)cn;
            sh_ssq = (double)(long long)sq * INV_SSQ_SCALE;
        }
    }
    __syncthreads();

    if (threadIdx.x < NFEAT) {
        long long tot = (long long)(redS[0][f] + redS[1][f] + redS[2][f] + redS[3][f]);
        double cnt = sh_cnt;
        double mean = (cnt > 0.0) ? ((double)tot * INV_SUM_SCALE) / cnt : 0.0;
        g_means64[c * NFEAT + f]  = mean;
        g_means64T[f * NCLUST + c] = mean;
        g_means32[c * NFEAT + f]  = (float)mean;
        smean[f] = mean;
    }
    __syncthreads();
    if (threadIdx.x == 0) {
        double tn = 0.0;
        for (int q = 0; q < NFEAT; ++q) tn += smean[q] * smean[q];
        double cnt = sh_cnt;
        double var = (cnt > 0.0) ? sh_ssq / cnt - tn : 0.0;
        if (var < 0.0) var = 0.0;
        double sd = sqrt(var);
        g_tn64[c] = tn; g_std64[c] = sd; g_std32[c] = (float)sd;
        g_cnt[c] = (float)cnt;
    }
}

// ---------------- A3: median, validity, thresholds, + bf16 template pre-convert ----------------
__global__ __launch_bounds__(256) void kmedian() {
    __shared__ float svals[NCLUST];
    __shared__ int   svalid[NCLUST];
    __shared__ float mred[2];
    int t = threadIdx.x;
    if (t == 0) { mred[0] = 0.f; mred[1] = 0.f; }
    float cnt = g_cnt[t];
    int v0 = (cnt > 0.f) ? 1 : 0;
    float sd = g_std32[t];
    svals[t] = sd; svalid[t] = v0;
    __syncthreads();

    int m = 0, rank = 0;
    for (int jj = 0; jj < NCLUST; ++jj) {
        if (svalid[jj]) {
            ++m;
            float sj = svals[jj];
            if (sj < sd || (sj == sd && jj < t)) ++rank;
        }
    }
    if (v0) {
        if (rank == (m - 1) / 2) mred[0] = sd;
        if (rank == m / 2)       mred[1] = sd;
    }
    __syncthreads();
    float med = 0.5f * (mred[0] + mred[1]);

    int valid = v0 && (sd <= 3.0f * med);
    double sd64 = g_std64[t];
    float thr2 = valid ? (float)((1.5 * sd64) * (1.5 * sd64)) : -1.0f;
    g_valid[t] = valid;
    g_ktab[t]  = make_float2((float)g_tn64[t], thr2);

    // pre-convert templates to bf16 in the SWIZZLED layout (once, not per kmatch block)
    for (int q = threadIdx.x; q < NCLUST * 8; q += 256) {
        int c = q >> 3, g = q & 7;
        float4 u0 = *(const float4*)&g_means32[c * NFEAT + g * 8];
        float4 u1 = *(const float4*)&g_means32[c * NFEAT + g * 8 + 4];
        short8v h;
        h[0] = (short)f2bf(u0.x); h[1] = (short)f2bf(u0.y);
        h[2] = (short)f2bf(u0.z); h[3] = (short)f2bf(u0.w);
        h[4] = (short)f2bf(u1.x); h[5] = (short)f2bf(u1.y);
        h[6] = (short)f2bf(u1.z); h[7] = (short)f2bf(u1.w);
        unsigned byteoff = (unsigned)c * 128u + (((unsigned)g * 16u) ^ (((unsigned)c & 7u) << 4));
        *(short8v*)((char*)g_tmplbf + byteoff) = h;
    }
}

// ---------------- C: MFMA bulk min pass, 256 spikes per block ----------------
// mfma_f32_16x16x32_bf16: A lane l -> row=l&15, k=(l>>4)*8+j ; B lane l -> col=l&15, same k map.
// D lane l, reg r -> row=(l>>4)*4+r, col=l&15  [verified layout, m89]
__global__ __launch_bounds__(256) void kmatch(const float* __restrict__ spikes,
                                              const int* __restrict__ sidx,
                                              const unsigned char* __restrict__ midx,
                                              float* __restrict__ out, int n) {
    __shared__ __align__(16) unsigned short tml[NCLUST * NFEAT]; // 32 KiB swizzled bf16
    __shared__ float2 ktab_sh[NCLUST];

    // stage pre-swizzled templates: linear 16B copies
    for (int idx = threadIdx.x * 8; idx < NCLUST * NFEAT; idx += 256 * 8)
        *(short8v*)&tml[idx] = *(const short8v*)&g_tmplbf[idx];
    if (threadIdx.x < NCLUST) ktab_sh[threadIdx.x] = g_ktab[threadIdx.x];
    __syncthreads();

    const int lane = threadIdx.x & 63, wave = threadIdx.x >> 6;
    const int row  = lane & 15, grp = lane >> 4;
    const int i0w  = blockIdx.x * 256 + wave * 64;   // this wave's 64 spikes

    #pragma unroll 1
    for (int sb = 0; sb < 4; ++sb) {
        const int i0 = i0w + sb * 16;

        // ---- A fragments (spikes straight from global, f32 -> bf16) ----
        int ri = i0 + row;
        int rc = (ri < n) ? ri : (n - 1);
        const float* sp = spikes + (size_t)rc * NFEAT + grp * 8;
        float4 a0 = *(const float4*)(sp);
        float4 a1 = *(const float4*)(sp + 4);
        float4 a2 = *(const float4*)(sp + 32);
        float4 a3 = *(const float4*)(sp + 36);
        short8v af0, af1;
        af0[0] = (short)f2bf(a0.x); af0[1] = (short)f2bf(a0.y);
        af0[2] = (short)f2bf(a0.z); af0[3] = (short)f2bf(a0.w);
        af0[4] = (short)f2bf(a1.x); af0[5] = (short)f2bf(a1.y);
        af0[6] = (short)f2bf(a1.z); af0[7] = (short)f2bf(a1.w);
        af1[0] = (short)f2bf(a2.x); af1[1] = (short)f2bf(a2.y);
        af1[2] = (short)f2bf(a2.z); af1[3] = (short)f2bf(a2.w);
        af1[4] = (short)f2bf(a3.x); af1[5] = (short)f2bf(a3.y);
        af1[6] = (short)f2bf(a3.z); af1[7] = (short)f2bf(a3.w);

        // sn (|s|^2) in f32 from ORIGINAL f32 values; reduce across the 4 k-groups
        float pss = a0.x*a0.x + a0.y*a0.y + a0.z*a0.z + a0.w*a0.w
                  + a1.x*a1.x + a1.y*a1.y + a1.z*a1.z + a1.w*a1.w
                  + a2.x*a2.x + a2.y*a2.y + a2.z*a2.z + a2.w*a2.w
                  + a3.x*a3.x + a3.y*a3.y + a3.z*a3.z + a3.w*a3.w;
        pss += __shfl_xor(pss, 16);
        pss += __shfl_xor(pss, 32);          // now sn of row `row` on every lane

        float snr[4];
        #pragma unroll
        for (int r = 0; r < 4; ++r) snr[r] = __shfl(pss, grp * 4 + r);

        float d2min[4] = {3.4e38f, 3.4e38f, 3.4e38f, 3.4e38f};

        #pragma unroll 2
        for (int nt = 0; nt < 16; ++nt) {
            int c = nt * 16 + row;
            unsigned co = (unsigned)c * 128u;
            unsigned sw = (((unsigned)c & 7u) << 4);
            short8v b0 = *(short8v*)((char*)tml + (co + (((unsigned)grp * 16u) ^ sw)));
            short8v b1 = *(short8v*)((char*)tml + (co + ((((unsigned)grp + 4u) * 16u) ^ sw)));
            float4v acc = {0.f, 0.f, 0.f, 0.f};
            acc = __builtin_amdgcn_mfma_f32_16x16x32_bf16(af0, b0, acc, 0, 0, 0);
            acc = __builtin_amdgcn_mfma_f32_16x16x32_bf16(af1, b1, acc, 0, 0, 0);
            float2 kt = ktab_sh[c];
            #pragma unroll
            for (int r = 0; r < 4; ++r) {
                float d2 = (snr[r] - 2.0f * acc[r]) + kt.x;
                if (!(d2 > kt.y)) d2min[r] = fminf(d2min[r], d2);  // thr2=-1 => masked
            }
        }

        // min over the 16 cluster-lanes (xor 1,2,4,8)
        #pragma unroll
        for (int o = 1; o < 16; o <<= 1) {
            #pragma unroll
            for (int r = 0; r < 4; ++r) d2min[r] = fminf(d2min[r], __shfl_xor(d2min[r], o));
        }
        if (row == 0) {
            #pragma unroll
            for (int r = 0; r < 4; ++r) {
                int i = i0 + grp * 4 + r;
                if (i < n) {
                    float dm = d2min[r];
                    out[2 * (size_t)n + i] = (dm > 1e37f) ? BIGF : sqrtf(fmaxf(dm, 0.f));
                }
            }
        }
    }

    // pass-through outputs + unmatched list (256 threads cover this block's 256 spikes)
    int i = blockIdx.x * 256 + threadIdx.x;
    if (i < n) {
        int si = sidx[i];
        out[i]             = (float)si;
        out[(size_t)n + i] = midx[i] ? 1.0f : 0.0f;
        if (si == 0) {
            int p = atomicAdd(&g_nlist, 1);
            if (p < 1000000) g_list[p] = i;
        }
    }
}

// ---------------- D: precise f64 argmin, LANE = CLUSTER ----------------
// R7 bug: lane=feature meant a 6-deep dependent f64 shfl butterfly PER CLUSTER
// (256x per spike) -> 181us of serial DS-pipe chains. Now lane l owns clusters
// {l, l+64, l+128, l+192}; per feature: one independent broadcast shfl + 4 FMAs
// from the transposed f64 table (coalesced, L2-hot). One argmin butterfly per
// spike at the end, with (dist, index) tie-break == first-min-index semantics.
__global__ __launch_bounds__(256) void kprecise(const float* __restrict__ spikes,
                                                float* __restrict__ out, int n) {
    const int lane  = threadIdx.x & 63;
    const int gwave = (blockIdx.x * 256 + threadIdx.x) >> 6;
    const int nwave = (gridDim.x * 256) >> 6;
    const int nt    = g_nlist;

    // per-lane cluster constants (c = q*64 + lane), coalesced loads
    double tn[4], thr[4]; int vld[4];
    #pragma unroll
    for (int q = 0; q < 4; ++q) {
        int c = q * 64 + lane;
        tn[q]  = g_tn64[c];
        thr[q] = 1.5 * g_std64[c];
        vld[q] = g_valid[c];
    }

    for (int t = gwave; t < nt; t += nwave) {
        const int i = g_list[t];
        const double sf = (double)spikes[(size_t)i * NFEAT + lane];

        double sn = sf * sf;                 // once per spike
        #pragma unroll
        for (int o = 32; o; o >>= 1) sn += __shfl_xor(sn, o);

        double d0 = 0.0, d1 = 0.0, d2a = 0.0, d3 = 0.0;
        #pragma unroll 16
        for (int f = 0; f < NFEAT; ++f) {
            double b = __shfl(sf, f);        // independent across f
            const double* mrow = &g_means64T[(size_t)f * NCLUST + lane];
            d0 = fma(b, mrow[0],   d0);
            d1 = fma(b, mrow[64],  d1);
            d2a = fma(b, mrow[128], d2a);
            d3 = fma(b, mrow[192], d3);
        }
        double dot[4] = {d0, d1, d2a, d3};

        double dmin = 1e30; int best = 0;
        #pragma unroll
        for (int q = 0; q < 4; ++q) {        // ascending q => ascending cluster id
            if (!vld[q]) continue;
            double d2 = (sn - 2.0 * dot[q]) + tn[q];
            double dist = sqrt(fmax(d2, 0.0));
            if (dist > thr[q]) continue;
            if (dist < dmin) { dmin = dist; best = q * 64 + lane + 1; }
        }

        // cross-lane argmin with first-index tie-break
        #pragma unroll
        for (int o = 32; o; o >>= 1) {
            double od = __shfl_xor(dmin, o);
            int    ob = __shfl_xor(best, o);
            if (od < dmin || (od == dmin && ob < best)) { dmin = od; best = ob; }
        }

        if (dmin >= 256.0) best = 0;   // FIRST_MATCH_MAX_DIST * N_SAMPLES

        if (lane == 0) {
            out[i]                 = (float)best;
            out[(size_t)n + i]     = (best != 0) ? 1.0f : 0.0f;
            out[2 * (size_t)n + i] = (float)dmin;
        }
    }
}

extern "C" void kernel_launch(void* const* d_in, const int* in_sizes, int n_in,
                              void* d_out, int out_size, void* d_ws, size_t ws_size,
                              hipStream_t stream) {
    const float*         spikes = (const float*)d_in[0];
    const int*           sidx   = (const int*)d_in[1];
    const unsigned char* midx   = (const unsigned char*)d_in[2];
    float*               out    = (float*)d_out;
    const int n = in_sizes[1];

    kzero<<<1, 64, 0, stream>>>();
    kstats<<<NBLK_A, 1024, 0, stream>>>(spikes, sidx, n);
    kfinal<<<NCLUST, 256, 0, stream>>>();
    kmedian<<<1, 256, 0, stream>>>();
    int nblk = (n + 255) / 256;
    kmatch<<<nblk, 256, 0, stream>>>(spikes, sidx, midx, out, n);
    kprecise<<<1024, 256, 0, stream>>>(spikes, out, n);
}